// Round 1
// baseline (118.857 us; speedup 1.0000x reference)
//
#include <hip/hip_runtime.h>

// Dims (fixed by reference setup): B=64, R=5, N=512, A=64, U=128
typedef __attribute__((ext_vector_type(4))) float f32x4;
typedef __attribute__((ext_vector_type(8))) short s16x8;
typedef __attribute__((ext_vector_type(4))) short s16x4;

__device__ __forceinline__ unsigned short f2bf(float f) {
  union { float f; unsigned u; } v; v.f = f;
  return (unsigned short)((v.u + 0x7fffu + ((v.u >> 16) & 1u)) >> 16);  // RNE
}

// ---- K0a: features [64][512][64] f32 -> FT [64][64][512] bf16 (transpose+cvt) ----
__global__ void k_ft(const float* __restrict__ F, unsigned short* __restrict__ FT) {
  __shared__ float t[64][65];
  const int b  = blockIdx.x >> 3;
  const int m0 = (blockIdx.x & 7) * 64;
  const int tid = threadIdx.x;  // 256
  {
    const int row = tid >> 2, ac = (tid & 3) * 16;
    const float* src = F + ((size_t)b * 512 + m0 + row) * 64 + ac;
    #pragma unroll
    for (int j = 0; j < 4; ++j) {
      f32x4 v = *(const f32x4*)(src + j * 4);
      t[row][ac + j * 4 + 0] = v[0]; t[row][ac + j * 4 + 1] = v[1];
      t[row][ac + j * 4 + 2] = v[2]; t[row][ac + j * 4 + 3] = v[3];
    }
  }
  __syncthreads();
  {
    const int a = tid >> 2, mc = (tid & 3) * 16;
    unsigned short* dst = FT + ((size_t)b * 64 + a) * 512 + m0 + mc;
    s16x8 p0, p1;
    #pragma unroll
    for (int j = 0; j < 8; ++j) {
      p0[j] = (short)f2bf(t[mc + j][a]);
      p1[j] = (short)f2bf(t[mc + 8 + j][a]);
    }
    *(s16x8*)(dst) = p0;
    *(s16x8*)(dst + 8) = p1;
  }
}

// ---- K0b: kernel [5][64][128] f32 -> KT [128][320] bf16 ; bsum[u] = sum_r bias[r][0][u] ----
__global__ void k_kt(const float* __restrict__ K, const float* __restrict__ bias,
                     unsigned short* __restrict__ KT, float* __restrict__ bsum) {
  const int gtid = threadIdx.x + blockIdx.x * blockDim.x;
  for (int idx = gtid; idx < 128 * 320; idx += blockDim.x * gridDim.x) {
    const int u = idx / 320, ra = idx % 320;           // ra = r*64 + a
    KT[idx] = f2bf(K[(size_t)ra * 128 + u]);
  }
  if (gtid < 128) {
    float s = 0.f;
    #pragma unroll
    for (int r = 0; r < 5; ++r) s += bias[r * 128 + gtid];
    bsum[gtid] = s;
  }
}

// ---- K1: aggT GEMM. Per block: 64 adjacency rows, all 5 relations, K=512.
// D = FT_tile(A-op, a x m) * AdjT_tile(B-op, m x n)  => D[a][n] = agg[n][a]
// store agg as [b][n][r*64+a] bf16  (A-operand layout for K2)
__global__ __launch_bounds__(256, 2) void k_agg(const float* __restrict__ Adj,
                                                const unsigned short* __restrict__ FT,
                                                unsigned short* __restrict__ aggc) {
  const int b  = blockIdx.x >> 3;
  const int nt = blockIdx.x & 7;
  const int w  = threadIdx.x >> 6;       // wave 0..3
  const int l  = threadIdx.x & 63;
  const int l15 = l & 15, g = l >> 4;
  const int n = nt * 64 + w * 16 + l15;  // this lane's adjacency row / agg row

  const float* adjRow = Adj + (size_t)(b * 5) * 262144 + (size_t)n * 512 + g * 8;
  const unsigned short* ftp = FT + ((size_t)b * 64 + l15) * 512 + g * 8;

  f32x4 acc[5][4];
  #pragma unroll
  for (int r = 0; r < 5; ++r)
    #pragma unroll
    for (int at = 0; at < 4; ++at) acc[r][at] = (f32x4)0.f;

  #pragma unroll 2
  for (int ks = 0; ks < 16; ++ks) {
    s16x8 ffrag[4];
    #pragma unroll
    for (int at = 0; at < 4; ++at)
      ffrag[at] = *(const s16x8*)(ftp + at * 16 * 512 + ks * 32);
    #pragma unroll
    for (int r = 0; r < 5; ++r) {
      const float* ap = adjRow + (size_t)r * 262144 + ks * 32;
      f32x4 a0 = *(const f32x4*)(ap);
      f32x4 a1 = *(const f32x4*)(ap + 4);
      s16x8 bfrag;
      bfrag[0] = (short)f2bf(a0[0]); bfrag[1] = (short)f2bf(a0[1]);
      bfrag[2] = (short)f2bf(a0[2]); bfrag[3] = (short)f2bf(a0[3]);
      bfrag[4] = (short)f2bf(a1[0]); bfrag[5] = (short)f2bf(a1[1]);
      bfrag[6] = (short)f2bf(a1[2]); bfrag[7] = (short)f2bf(a1[3]);
      #pragma unroll
      for (int at = 0; at < 4; ++at)
        acc[r][at] = __builtin_amdgcn_mfma_f32_16x16x32_bf16(ffrag[at], bfrag, acc[r][at], 0, 0, 0);
    }
  }

  // D[a][n]: lane holds a = at*16 + 4g + t (t=0..3), n fixed = l15-row.
  unsigned short* op = aggc + ((size_t)(b * 512) + n) * 320;
  #pragma unroll
  for (int r = 0; r < 5; ++r)
    #pragma unroll
    for (int at = 0; at < 4; ++at) {
      s16x4 pk;
      pk[0] = (short)f2bf(acc[r][at][0]); pk[1] = (short)f2bf(acc[r][at][1]);
      pk[2] = (short)f2bf(acc[r][at][2]); pk[3] = (short)f2bf(acc[r][at][3]);
      *(s16x4*)(op + r * 64 + at * 16 + g * 4) = pk;
    }
}

// ---- K2: out[b][n][u] = relu( aggc[b][n][:] @ KT[u][:]^T + bsum[u] ), K-dim 320 ----
__global__ __launch_bounds__(256, 2) void k_out(const unsigned short* __restrict__ aggc,
                                                const unsigned short* __restrict__ KT,
                                                const float* __restrict__ bsum,
                                                float* __restrict__ out) {
  const int b   = blockIdx.x >> 3;
  const int nt8 = blockIdx.x & 7;        // 64-row tile
  const int w   = threadIdx.x >> 6;
  const int wn  = w >> 1, wu = w & 1;    // 2x 32-row strips, 2x 64-col strips
  const int l   = threadIdx.x & 63;
  const int l15 = l & 15, g = l >> 4;

  const int n0 = nt8 * 64 + wn * 32;
  const int u0 = wu * 64;

  const unsigned short* ap = aggc + ((size_t)(b * 512) + n0 + l15) * 320 + g * 8;
  const unsigned short* kp = KT + (size_t)(u0 + l15) * 320 + g * 8;

  f32x4 acc[2][4];
  #pragma unroll
  for (int i = 0; i < 2; ++i)
    #pragma unroll
    for (int j = 0; j < 4; ++j) acc[i][j] = (f32x4)0.f;

  #pragma unroll 2
  for (int ks = 0; ks < 10; ++ks) {
    s16x8 af[2];
    af[0] = *(const s16x8*)(ap + ks * 32);
    af[1] = *(const s16x8*)(ap + 16 * 320 + ks * 32);
    s16x8 bf[4];
    #pragma unroll
    for (int ut = 0; ut < 4; ++ut)
      bf[ut] = *(const s16x8*)(kp + ut * 16 * 320 + ks * 32);
    #pragma unroll
    for (int i = 0; i < 2; ++i)
      #pragma unroll
      for (int ut = 0; ut < 4; ++ut)
        acc[i][ut] = __builtin_amdgcn_mfma_f32_16x16x32_bf16(af[i], bf[ut], acc[i][ut], 0, 0, 0);
  }

  #pragma unroll
  for (int ut = 0; ut < 4; ++ut) {
    const int col = u0 + ut * 16 + l15;
    const float bs = bsum[col];
    #pragma unroll
    for (int i = 0; i < 2; ++i)
      #pragma unroll
      for (int t = 0; t < 4; ++t) {
        const int row = n0 + i * 16 + g * 4 + t;
        float vv = acc[i][ut][t] + bs;
        out[((size_t)b * 512 + row) * 128 + col] = vv > 0.f ? vv : 0.f;
      }
  }
}

extern "C" void kernel_launch(void* const* d_in, const int* in_sizes, int n_in,
                              void* d_out, int out_size, void* d_ws, size_t ws_size,
                              hipStream_t stream) {
  const float* adj  = (const float*)d_in[0];   // [64][5][512][512]
  const float* feat = (const float*)d_in[1];   // [64][512][64]
  const float* kern = (const float*)d_in[2];   // [5][64][128]
  const float* bias = (const float*)d_in[3];   // [5][1][128]
  float* out = (float*)d_out;                  // [64][512][128] f32

  char* ws = (char*)d_ws;
  unsigned short* aggc = (unsigned short*)ws;                         // 64*512*320*2 = 20,971,520 B
  unsigned short* FT   = (unsigned short*)(ws + 20971520);            // 64*64*512*2 =  4,194,304 B
  unsigned short* KT   = (unsigned short*)(ws + 20971520 + 4194304);  // 128*320*2   =     81,920 B
  float*          bsum = (float*)(ws + 20971520 + 4194304 + 81920);   // 128*4       =        512 B

  hipLaunchKernelGGL(k_ft,  dim3(512), dim3(256), 0, stream, feat, FT);
  hipLaunchKernelGGL(k_kt,  dim3(160), dim3(256), 0, stream, kern, bias, KT, bsum);
  hipLaunchKernelGGL(k_agg, dim3(512), dim3(256), 0, stream, adj, FT, aggc);
  hipLaunchKernelGGL(k_out, dim3(512), dim3(256), 0, stream, aggc, KT, bsum, out);
  (void)in_sizes; (void)n_in; (void)out_size; (void)ws_size;
}

// Round 2
// 101.441 us; speedup vs baseline: 1.1717x; 1.1717x over previous
//
#include <hip/hip_runtime.h>
#include <hip/hip_bf16.h>

// Dims (fixed by reference setup): B=64, R=5, N=512, A=64, U=128
typedef __attribute__((ext_vector_type(4))) float f32x4;
typedef __attribute__((ext_vector_type(8))) short s16x8;
typedef __attribute__((ext_vector_type(4))) short s16x4;

__device__ __forceinline__ unsigned short f2bf(float f) {
  __hip_bfloat16 h = __float2bfloat16(f);   // compiler packs pairs into v_cvt_pk_bf16_f32 (m240)
  return __builtin_bit_cast(unsigned short, h);
}

// ---- K0a: features [64][512][64] f32 -> FT [64][64][512] bf16 (transpose+cvt) ----
__global__ void k_ft(const float* __restrict__ F, unsigned short* __restrict__ FT) {
  __shared__ float t[64][65];
  const int b  = blockIdx.x >> 3;
  const int m0 = (blockIdx.x & 7) * 64;
  const int tid = threadIdx.x;  // 256
  {
    const int row = tid >> 2, ac = (tid & 3) * 16;
    const float* src = F + ((size_t)b * 512 + m0 + row) * 64 + ac;
    #pragma unroll
    for (int j = 0; j < 4; ++j) {
      f32x4 v = *(const f32x4*)(src + j * 4);
      t[row][ac + j * 4 + 0] = v[0]; t[row][ac + j * 4 + 1] = v[1];
      t[row][ac + j * 4 + 2] = v[2]; t[row][ac + j * 4 + 3] = v[3];
    }
  }
  __syncthreads();
  {
    const int a = tid >> 2, mc = (tid & 3) * 16;
    unsigned short* dst = FT + ((size_t)b * 64 + a) * 512 + m0 + mc;
    s16x8 p0, p1;
    #pragma unroll
    for (int j = 0; j < 8; ++j) {
      p0[j] = (short)f2bf(t[mc + j][a]);
      p1[j] = (short)f2bf(t[mc + 8 + j][a]);
    }
    *(s16x8*)(dst) = p0;
    *(s16x8*)(dst + 8) = p1;
  }
}

// ---- K0b: kernel [5][64][128] f32 -> KT [128][320] bf16 ; bsum[u] = sum_r bias[r][0][u] ----
__global__ void k_kt(const float* __restrict__ K, const float* __restrict__ bias,
                     unsigned short* __restrict__ KT, float* __restrict__ bsum) {
  const int gtid = threadIdx.x + blockIdx.x * blockDim.x;
  for (int idx = gtid; idx < 128 * 320; idx += blockDim.x * gridDim.x) {
    const int u = idx / 320, ra = idx % 320;           // ra = r*64 + a
    KT[idx] = f2bf(K[(size_t)ra * 128 + u]);
  }
  if (gtid < 128) {
    float s = 0.f;
    #pragma unroll
    for (int r = 0; r < 5; ++r) s += bias[r * 128 + gtid];
    bsum[gtid] = s;
  }
}

// ---- Fused: agg GEMM (K=512, 5 relations) -> LDS -> out GEMM (K=320) + bias + relu ----
// Phase 1: D1 = FT_tile(A: a x m) * AdjT_tile(B: m x n) => D1[a][n] = agg[n][a]
// Phase 2: stage agg tile [64 n][320 ra] bf16 in LDS (pad to 328: row stride 656B, bank shift 4)
// Phase 3: D2 = agg_tile(A: n x ra) * KT(B: ra x u) => out[n][u], +bias, relu
__global__ __launch_bounds__(256, 3) void k_fused(const float* __restrict__ Adj,
                                                  const unsigned short* __restrict__ FT,
                                                  const unsigned short* __restrict__ KT,
                                                  const float* __restrict__ bsum,
                                                  float* __restrict__ out) {
  __shared__ unsigned short ag[64][328];
  const int b  = blockIdx.x >> 3;
  const int nt = blockIdx.x & 7;
  const int w  = threadIdx.x >> 6;       // wave 0..3, owns 16 n-rows
  const int l  = threadIdx.x & 63;
  const int l15 = l & 15, g = l >> 4;
  const int n = nt * 64 + w * 16 + l15;

  const float* adjRow = Adj + (size_t)(b * 5) * 262144 + (size_t)n * 512 + g * 8;
  const unsigned short* ftp = FT + ((size_t)b * 64 + l15) * 512 + g * 8;

  f32x4 acc[5][4];
  #pragma unroll
  for (int r = 0; r < 5; ++r)
    #pragma unroll
    for (int at = 0; at < 4; ++at) acc[r][at] = (f32x4)0.f;

  #pragma unroll 2
  for (int ks = 0; ks < 16; ++ks) {
    s16x8 ffrag[4];
    #pragma unroll
    for (int at = 0; at < 4; ++at)
      ffrag[at] = *(const s16x8*)(ftp + at * 16 * 512 + ks * 32);
    #pragma unroll
    for (int r = 0; r < 5; ++r) {
      const float* ap = adjRow + (size_t)r * 262144 + ks * 32;
      f32x4 a0 = *(const f32x4*)(ap);
      f32x4 a1 = *(const f32x4*)(ap + 4);
      s16x8 bfrag;
      #pragma unroll
      for (int j = 0; j < 4; ++j) {
        bfrag[j]     = (short)f2bf(a0[j]);
        bfrag[4 + j] = (short)f2bf(a1[j]);
      }
      #pragma unroll
      for (int at = 0; at < 4; ++at)
        acc[r][at] = __builtin_amdgcn_mfma_f32_16x16x32_bf16(ffrag[at], bfrag, acc[r][at], 0, 0, 0);
    }
  }

  // Phase 2: lane holds agg[n = w*16+l15][a = at*16 + g*4 + t] (D: col=lane&15, row=(lane>>4)*4+t)
  #pragma unroll
  for (int r = 0; r < 5; ++r)
    #pragma unroll
    for (int at = 0; at < 4; ++at) {
      s16x4 pk;
      pk[0] = (short)f2bf(acc[r][at][0]); pk[1] = (short)f2bf(acc[r][at][1]);
      pk[2] = (short)f2bf(acc[r][at][2]); pk[3] = (short)f2bf(acc[r][at][3]);
      *(s16x4*)&ag[w * 16 + l15][r * 64 + at * 16 + g * 4] = pk;
    }
  __syncthreads();

  // Phase 3: wave w -> rows w*16.., all 128 u. A from LDS, B = KT (L2-resident).
  const unsigned short* kp = KT + (size_t)l15 * 320 + g * 8;
  f32x4 o[8];
  #pragma unroll
  for (int ut = 0; ut < 8; ++ut) o[ut] = (f32x4)0.f;

  #pragma unroll 2
  for (int ks = 0; ks < 10; ++ks) {
    s16x8 af = *(const s16x8*)&ag[w * 16 + l15][ks * 32 + g * 8];
    #pragma unroll
    for (int ut = 0; ut < 8; ++ut) {
      s16x8 bfr = *(const s16x8*)(kp + (size_t)ut * 16 * 320 + ks * 32);
      o[ut] = __builtin_amdgcn_mfma_f32_16x16x32_bf16(af, bfr, o[ut], 0, 0, 0);
    }
  }

  // D2: col = l15 -> u = ut*16+l15 ; row = g*4+t -> n = nt*64 + w*16 + g*4 + t
  #pragma unroll
  for (int ut = 0; ut < 8; ++ut) {
    const int u = ut * 16 + l15;
    const float bs = bsum[u];
    float* op = out + ((size_t)(b * 512 + nt * 64 + w * 16 + g * 4)) * 128 + u;
    #pragma unroll
    for (int t = 0; t < 4; ++t) {
      float vv = o[ut][t] + bs;
      op[(size_t)t * 128] = vv > 0.f ? vv : 0.f;
    }
  }
}

extern "C" void kernel_launch(void* const* d_in, const int* in_sizes, int n_in,
                              void* d_out, int out_size, void* d_ws, size_t ws_size,
                              hipStream_t stream) {
  const float* adj  = (const float*)d_in[0];   // [64][5][512][512]
  const float* feat = (const float*)d_in[1];   // [64][512][64]
  const float* kern = (const float*)d_in[2];   // [5][64][128]
  const float* bias = (const float*)d_in[3];   // [5][1][128]
  float* out = (float*)d_out;                  // [64][512][128] f32

  char* ws = (char*)d_ws;
  unsigned short* FT   = (unsigned short*)ws;                  // 64*64*512*2 = 4,194,304 B
  unsigned short* KT   = (unsigned short*)(ws + 4194304);      // 128*320*2   =    81,920 B
  float*          bsum = (float*)(ws + 4194304 + 81920);       // 128*4       =       512 B

  hipLaunchKernelGGL(k_ft,    dim3(512), dim3(256), 0, stream, feat, FT);
  hipLaunchKernelGGL(k_kt,    dim3(160), dim3(256), 0, stream, kern, bias, KT, bsum);
  hipLaunchKernelGGL(k_fused, dim3(512), dim3(256), 0, stream, adj, FT, KT, bsum, out);
  (void)in_sizes; (void)n_in; (void)out_size; (void)ws_size;
}